// Round 5
// baseline (743.156 us; speedup 1.0000x reference)
//
#include <hip/hip_runtime.h>
#include <math.h>

typedef short s16x8 __attribute__((ext_vector_type(8)));
typedef float f32x4 __attribute__((ext_vector_type(4)));
typedef unsigned u32x4 __attribute__((ext_vector_type(4)));
typedef unsigned short u16;

#define S_LEN 2048
#define HID_DIM 4096
#define NH_Q 32
#define NKV_H 8
#define DHEAD 128

__device__ __forceinline__ u16 f2bf(float f) {
  unsigned u = __builtin_bit_cast(unsigned, f);
  u += 0x7fffu + ((u >> 16) & 1u);
  return (u16)(u >> 16);
}

// async global -> LDS, 16B per lane; lds base must be wave-uniform
__device__ __forceinline__ void gload16(const u16* g, u16* l) {
  __builtin_amdgcn_global_load_lds(
      (const __attribute__((address_space(1))) void*)g,
      (__attribute__((address_space(3))) void*)l, 16, 0, 0);
}

// ---------------- f32 -> bf16 bulk convert ----------------
__global__ void cvt_kernel(const float* __restrict__ in, u16* __restrict__ out, int n4) {
  int stride = gridDim.x * blockDim.x;
  for (int i = blockIdx.x * blockDim.x + threadIdx.x; i < n4; i += stride) {
    float4 f = ((const float4*)in)[i];
    uint2 o;
    o.x = (unsigned)f2bf(f.x) | ((unsigned)f2bf(f.y) << 16);
    o.y = (unsigned)f2bf(f.z) | ((unsigned)f2bf(f.w) << 16);
    ((uint2*)out)[i] = o;
  }
}

// ---------------- RoPE tables: cos/sin [S][64] ----------------
__global__ void rope_table_kernel(const int* __restrict__ positions,
                                  float* __restrict__ cos_t, float* __restrict__ sin_t) {
  int idx = blockIdx.x * 256 + threadIdx.x;
  if (idx >= S_LEN * 64) return;
  int s = idx >> 6, j = idx & 63;
  float pos = (float)positions[s];
  float inv = expf(-(float)j * (9.210340371976184f / 64.0f));
  float ang = pos * inv;
  float sv, cv;
  sincosf(ang, &sv, &cv);
  cos_t[idx] = cv;
  sin_t[idx] = sv;
}

// ---------------- m97-structure GEMM (bf16 in): C = A[M][K] * B[N][K]^T ----
// 128x128 tile, BK=32, global_load_lds staging, linear LDS, 4 waves (2x2).
// Wave covers 64 rows x (two 32-col stripes at wc*32 and wc*32+64) so RoPE
// pairs (j, j+64) stay in-wave.  EPI: 0 = f32 row-major; 2 = RoPE q out
// ([b][h][s][d], Hh heads); 3 = fused kv (k RoPE | v transposed [b][h][d][s])
template<int EPI>
__global__ __launch_bounds__(256) void gemm97_kernel(
    const u16* __restrict__ A, const u16* __restrict__ B,
    void* __restrict__ outp, void* __restrict__ outp2, int M, int N, int K,
    const float* __restrict__ cos_t, const float* __restrict__ sin_t, int Hh) {
  __shared__ u16 As[128 * 32];
  __shared__ u16 Bs[128 * 32];
  const int t = threadIdx.x;
  const int wave = t >> 6, lane = t & 63;
  const int l15 = lane & 15, lhi = lane >> 4;
  const int wr = wave >> 1, wc = wave & 1;
  // bijective XCD swizzle (grids are multiples of 8)
  const int gx = gridDim.x;
  const int nwg = gx * gridDim.y;
  const int id = blockIdx.y * gx + blockIdx.x;
  const int swz = (id & 7) * (nwg >> 3) + (id >> 3);
  const int bm = (swz / gx) * 128, bn = (swz % gx) * 128;

  // staging: 16B-unit u covers (row = u>>2, chunk = u&3); lane handles
  // u = wave*64+lane (half 0) and u+256 (half 1) for each of A and B.
  const size_t a0 = (size_t)(bm + ((wave * 64 + lane) >> 2)) * K + (lane & 3) * 8;
  const size_t a1 = (size_t)(bm + 64 + ((wave * 64 + lane) >> 2)) * K + (lane & 3) * 8;
  const size_t b0 = (size_t)(bn + ((wave * 64 + lane) >> 2)) * K + (lane & 3) * 8;
  const size_t b1 = (size_t)(bn + 64 + ((wave * 64 + lane) >> 2)) * K + (lane & 3) * 8;
  u16* AsL0 = &As[wave * 512];
  u16* AsL1 = &As[2048 + wave * 512];
  u16* BsL0 = &Bs[wave * 512];
  u16* BsL1 = &Bs[2048 + wave * 512];

  const f32x4 fz = {0.f, 0.f, 0.f, 0.f};
  f32x4 acc[4][4];
#pragma unroll
  for (int mf = 0; mf < 4; ++mf)
#pragma unroll
    for (int nf = 0; nf < 4; ++nf) acc[mf][nf] = fz;

  for (int kt = 0; kt < K; kt += 32) {
    __syncthreads();  // previous iteration's readers done
    gload16(A + a0 + kt, AsL0);
    gload16(A + a1 + kt, AsL1);
    gload16(B + b0 + kt, BsL0);
    gload16(B + b1 + kt, BsL1);
    __syncthreads();  // compiler drains vmcnt before this barrier
    s16x8 a[4], b[4];
#pragma unroll
    for (int mf = 0; mf < 4; ++mf)
      a[mf] = *(const s16x8*)&As[(wr * 64 + mf * 16 + l15) * 32 + lhi * 8];
#pragma unroll
    for (int nf = 0; nf < 4; ++nf)
      b[nf] = *(const s16x8*)&Bs[(wc * 32 + (nf & 1) * 16 + (nf >> 1) * 64 + l15) * 32 + lhi * 8];
#pragma unroll
    for (int mf = 0; mf < 4; ++mf)
#pragma unroll
      for (int nf = 0; nf < 4; ++nf)
        acc[mf][nf] = __builtin_amdgcn_mfma_f32_16x16x32_bf16(a[mf], b[nf], acc[mf][nf], 0, 0, 0);
  }

  // ---- epilogue ----
  if (EPI == 0) {
    float* C = (float*)outp;
#pragma unroll
    for (int mf = 0; mf < 4; ++mf)
#pragma unroll
      for (int nf = 0; nf < 4; ++nf) {
        int col = bn + wc * 32 + (nf & 1) * 16 + (nf >> 1) * 64 + l15;
        int rb = bm + wr * 64 + mf * 16 + lhi * 4;
#pragma unroll
        for (int i = 0; i < 4; ++i) C[(size_t)(rb + i) * N + col] = acc[mf][nf][i];
      }
  } else if (EPI == 2) {  // RoPE q: [b][h][s][d]
    u16* O = (u16*)outp;
    int h = bn >> 7;
#pragma unroll
    for (int mf = 0; mf < 4; ++mf)
#pragma unroll
      for (int nf = 0; nf < 2; ++nf) {
        int j = wc * 32 + nf * 16 + l15;  // 0..63; partner acc[mf][nf+2] = col j+64
        int rb = bm + wr * 64 + mf * 16 + lhi * 4;
#pragma unroll
        for (int i = 0; i < 4; ++i) {
          int m = rb + i;
          int b = m >> 11, srow = m & 2047;
          float c = cos_t[srow * 64 + j];
          float s = sin_t[srow * 64 + j];
          float x0 = acc[mf][nf][i];
          float x1 = acc[mf][nf + 2][i];
          size_t base = ((size_t)(b * Hh + h) * S_LEN + srow) * DHEAD;
          O[base + j] = f2bf(x0 * c - x1 * s);
          O[base + j + 64] = f2bf(x0 * s + x1 * c);
        }
      }
  } else {  // EPI == 3: fused k (RoPE, [b][h][s][d]) | v (transposed [b][h][d][s])
    if (bn < 1024) {
      u16* O = (u16*)outp;
      int h = bn >> 7;
#pragma unroll
      for (int mf = 0; mf < 4; ++mf)
#pragma unroll
        for (int nf = 0; nf < 2; ++nf) {
          int j = wc * 32 + nf * 16 + l15;
          int rb = bm + wr * 64 + mf * 16 + lhi * 4;
#pragma unroll
          for (int i = 0; i < 4; ++i) {
            int m = rb + i;
            int b = m >> 11, srow = m & 2047;
            float c = cos_t[srow * 64 + j];
            float s = sin_t[srow * 64 + j];
            float x0 = acc[mf][nf][i];
            float x1 = acc[mf][nf + 2][i];
            size_t base = ((size_t)(b * NKV_H + h) * S_LEN + srow) * DHEAD;
            O[base + j] = f2bf(x0 * c - x1 * s);
            O[base + j + 64] = f2bf(x0 * s + x1 * c);
          }
        }
    } else {
      u16* O = (u16*)outp2;
#pragma unroll
      for (int mf = 0; mf < 4; ++mf)
#pragma unroll
        for (int nf = 0; nf < 4; ++nf) {
          int col = bn - 1024 + wc * 32 + (nf & 1) * 16 + (nf >> 1) * 64 + l15;
          int h = col >> 7, d = col & 127;
          int rb = bm + wr * 64 + mf * 16 + lhi * 4;
#pragma unroll
          for (int i = 0; i < 4; ++i) {
            int m = rb + i;
            int b = m >> 11, srow = m & 2047;
            O[((size_t)(b * NKV_H + h) * DHEAD + d) * S_LEN + srow] = f2bf(acc[mf][nf][i]);
          }
        }
    }
  }
}

// ---------------- reg-staged GEMM (fallback path only) ----------------
// EPI: 0 = f32 row-major out; 2 = RoPE + bf16 out; 4 = bf16 transposed [b][h][d][s]
template<int EPI, bool ABF16, bool BBF16>
__global__ __launch_bounds__(256) void gemm_kernel(
    const void* __restrict__ Aptr, const void* __restrict__ Bptr,
    void* __restrict__ outp, void* __restrict__ outp2, int M, int N, int K,
    const float* __restrict__ cos_t, const float* __restrict__ sin_t, int Hh) {
  __shared__ u16 As[128][72];
  __shared__ u16 Bs[128][72];
  const int t = threadIdx.x;
  const int wave = t >> 6, lane = t & 63;
  const int l15 = lane & 15, lhi = lane >> 4;
  const int gx = gridDim.x;
  const int nwg = gx * gridDim.y;
  const int id = blockIdx.y * gx + blockIdx.x;
  const int swz = (id & 7) * (nwg >> 3) + (id >> 3);
  const int bm = (swz / gx) * 128, bn = (swz % gx) * 128;

  const f32x4 fz = {0.f, 0.f, 0.f, 0.f};
  f32x4 acc[2][8];
#pragma unroll
  for (int a0 = 0; a0 < 2; ++a0)
#pragma unroll
    for (int b0 = 0; b0 < 8; ++b0) acc[a0][b0] = fz;

  for (int kt = 0; kt < K; kt += 64) {
    __syncthreads();
    if (ABF16) {
      const u16* A = (const u16*)Aptr;
#pragma unroll
      for (int p = 0; p < 4; ++p) {
        int row = p * 32 + (t >> 3), kc = (t & 7) * 8;
        *(s16x8*)&As[row][kc] = *(const s16x8*)(A + (size_t)(bm + row) * K + kt + kc);
      }
    } else {
      const float* A = (const float*)Aptr;
#pragma unroll
      for (int p = 0; p < 8; ++p) {
        int row = p * 16 + (t >> 4), kc = (t & 15) * 4;
        float4 f = *(const float4*)(A + (size_t)(bm + row) * K + kt + kc);
        unsigned* dst = (unsigned*)&As[row][kc];
        dst[0] = (unsigned)f2bf(f.x) | ((unsigned)f2bf(f.y) << 16);
        dst[1] = (unsigned)f2bf(f.z) | ((unsigned)f2bf(f.w) << 16);
      }
    }
    if (BBF16) {
      const u16* Bw = (const u16*)Bptr;
#pragma unroll
      for (int p = 0; p < 4; ++p) {
        int row = p * 32 + (t >> 3), kc = (t & 7) * 8;
        *(s16x8*)&Bs[row][kc] = *(const s16x8*)(Bw + (size_t)(bn + row) * K + kt + kc);
      }
    } else {
      const float* Bw = (const float*)Bptr;
#pragma unroll
      for (int p = 0; p < 8; ++p) {
        int row = p * 16 + (t >> 4), kc = (t & 15) * 4;
        float4 f = *(const float4*)(Bw + (size_t)(bn + row) * K + kt + kc);
        unsigned* dst = (unsigned*)&Bs[row][kc];
        dst[0] = (unsigned)f2bf(f.x) | ((unsigned)f2bf(f.y) << 16);
        dst[1] = (unsigned)f2bf(f.z) | ((unsigned)f2bf(f.w) << 16);
      }
    }
    __syncthreads();
#pragma unroll
    for (int ks = 0; ks < 2; ++ks) {
      s16x8 bfr[8];
#pragma unroll
      for (int nf = 0; nf < 8; ++nf)
        bfr[nf] = *(const s16x8*)&Bs[nf * 16 + l15][ks * 32 + lhi * 8];
#pragma unroll
      for (int mf = 0; mf < 2; ++mf) {
        s16x8 a = *(const s16x8*)&As[wave * 32 + mf * 16 + l15][ks * 32 + lhi * 8];
#pragma unroll
        for (int nf = 0; nf < 8; ++nf)
          acc[mf][nf] = __builtin_amdgcn_mfma_f32_16x16x32_bf16(a, bfr[nf], acc[mf][nf], 0, 0, 0);
      }
    }
  }

  if (EPI == 0) {
    float* C = (float*)outp;
#pragma unroll
    for (int mf = 0; mf < 2; ++mf)
#pragma unroll
      for (int nf = 0; nf < 8; ++nf) {
        int col = bn + nf * 16 + l15;
        int rb = bm + wave * 32 + mf * 16 + lhi * 4;
#pragma unroll
        for (int i = 0; i < 4; ++i) C[(size_t)(rb + i) * N + col] = acc[mf][nf][i];
      }
  } else if (EPI == 2) {
    u16* O = (u16*)outp;
    int h = bn >> 7;
#pragma unroll
    for (int mf = 0; mf < 2; ++mf)
#pragma unroll
      for (int nf = 0; nf < 4; ++nf) {
        int j = nf * 16 + l15;
        int rb = bm + wave * 32 + mf * 16 + lhi * 4;
#pragma unroll
        for (int i = 0; i < 4; ++i) {
          int m = rb + i;
          int b = m >> 11, srow = m & 2047;
          float c = cos_t[srow * 64 + j];
          float s = sin_t[srow * 64 + j];
          float x0 = acc[mf][nf][i];
          float x1 = acc[mf][nf + 4][i];
          size_t base = ((size_t)(b * Hh + h) * S_LEN + srow) * DHEAD;
          O[base + j] = f2bf(x0 * c - x1 * s);
          O[base + j + 64] = f2bf(x0 * s + x1 * c);
        }
      }
  } else {  // EPI == 4: bf16 transposed [b][h][d][s]
    u16* O = (u16*)outp;
#pragma unroll
    for (int mf = 0; mf < 2; ++mf)
#pragma unroll
      for (int nf = 0; nf < 8; ++nf) {
        int col = bn + nf * 16 + l15;
        int h = col >> 7, d = col & 127;
        int rb = bm + wave * 32 + mf * 16 + lhi * 4;
#pragma unroll
        for (int i = 0; i < 4; ++i) {
          int m = rb + i;
          int b = m >> 11, srow = m & 2047;
          O[((size_t)(b * Hh + h) * DHEAD + d) * S_LEN + srow] = f2bf(acc[mf][nf][i]);
        }
      }
  }
}

// ---------------- Flash attention (causal, GQA) ----------------
// Paired q-tiles for perfect balance: block = pair (pi, 15-pi), each of 128 rows.
// grid: (8, NH, B) x 512 thr; swapped QK^T in-register softmax; V^T in global.
#define KIDX(r, c) (((r) * 128 + (c)) ^ (((r) & 7) << 3))
#define VIDX(d, kv) (((d) * 64 + (kv)) ^ (((d) & 7) << 3))
__global__ __launch_bounds__(512) void attn_kernel(
    const u16* __restrict__ q, const u16* __restrict__ k, const u16* __restrict__ vt,
    u16* __restrict__ ctx) {
  __shared__ u16 Ks[64 * 128];
  __shared__ u16 Vts[128 * 64];

  const int t = threadIdx.x;
  const int wave = t >> 6, lane = t & 63;
  const int l15 = lane & 15, lhi = lane >> 4;
  const int pi = blockIdx.x, h = blockIdx.y, b = blockIdx.z;
  const int kvh = h >> 2;
  const int qsub[2] = {pi, 15 - pi};
  const int ntiles = 32 - 2 * pi;

  const u16* qb = q + ((size_t)(b * NH_Q + h)) * S_LEN * DHEAD;
  const u16* kb = k + ((size_t)(b * NKV_H + kvh)) * S_LEN * DHEAD;
  const u16* vtb = vt + ((size_t)(b * NKV_H + kvh)) * DHEAD * S_LEN;

  s16x8 qf[2][4];
#pragma unroll
  for (int s = 0; s < 2; ++s)
#pragma unroll
    for (int ks = 0; ks < 4; ++ks)
      qf[s][ks] = *(const s16x8*)(qb + (size_t)(qsub[s] * 128 + wave * 16 + l15) * DHEAD +
                                  ks * 32 + lhi * 8);

  const f32x4 fz = {0.f, 0.f, 0.f, 0.f};
  f32x4 acc[2][8];
#pragma unroll
  for (int s = 0; s < 2; ++s)
#pragma unroll
    for (int i = 0; i < 8; ++i) acc[s][i] = fz;
  float mrow[2] = {-INFINITY, -INFINITY};
  float lsum[2] = {0.f, 0.f};

  const float scale = 0.08838834764831845f;

  const int sl0 = l15 | (((2 * lhi) & 3) << 4);
  const int sl1 = sl0 | 16;
  const bool hisel = (lhi & 2) != 0;

  const int krow = t >> 3, kd0 = (t & 7) * 16;
  const int vrow = t >> 2, vk0 = (t & 3) * 16;
  s16x8 kr0, kr1, vr0, vr1;
  {
    const u16* p = kb + (size_t)krow * DHEAD + kd0;
    kr0 = *(const s16x8*)p;
    kr1 = *(const s16x8*)(p + 8);
    const u16* pv = vtb + (size_t)vrow * S_LEN + vk0;
    vr0 = *(const s16x8*)pv;
    vr1 = *(const s16x8*)(pv + 8);
  }

  for (int tt = 0; tt < ntiles; ++tt) {
    __syncthreads();
    *(s16x8*)&Ks[KIDX(krow, kd0)] = kr0;
    *(s16x8*)&Ks[KIDX(krow, kd0 + 8)] = kr1;
    *(s16x8*)&Vts[VIDX(vrow, vk0)] = vr0;
    *(s16x8*)&Vts[VIDX(vrow, vk0 + 8)] = vr1;
    __syncthreads();
    if (tt + 1 < ntiles) {
      const u16* p = kb + (size_t)((tt + 1) * 64 + krow) * DHEAD + kd0;
      kr0 = *(const s16x8*)p;
      kr1 = *(const s16x8*)(p + 8);
      const u16* pv = vtb + (size_t)vrow * S_LEN + (tt + 1) * 64 + vk0;
      vr0 = *(const s16x8*)pv;
      vr1 = *(const s16x8*)(pv + 8);
    }

    const int kc_base = tt * 64;
#pragma unroll
    for (int s = 0; s < 2; ++s) {
      const int wmin = qsub[s] * 128 + wave * 16;
      if (kc_base > wmin + 15) continue;
      f32x4 sacc[4];
#pragma unroll
      for (int i = 0; i < 4; ++i) sacc[i] = fz;
      __builtin_amdgcn_s_setprio(1);
#pragma unroll
      for (int ks = 0; ks < 4; ++ks) {
#pragma unroll
        for (int nf = 0; nf < 4; ++nf) {
          s16x8 kf = *(const s16x8*)&Ks[KIDX(nf * 16 + l15, ks * 32 + lhi * 8)];
          sacc[nf] = __builtin_amdgcn_mfma_f32_16x16x32_bf16(kf, qf[s][ks], sacc[nf], 0, 0, 0);
        }
      }
      __builtin_amdgcn_s_setprio(0);

      const int qg = wmin + l15;
      float pmax = -INFINITY;
      if (kc_base + 63 > wmin) {
#pragma unroll
        for (int nf = 0; nf < 4; ++nf)
#pragma unroll
          for (int i = 0; i < 4; ++i) {
            int kv = kc_base + nf * 16 + lhi * 4 + i;
            float sv = sacc[nf][i] * scale;
            sv = (kv <= qg) ? sv : -INFINITY;
            sacc[nf][i] = sv;
            pmax = fmaxf(pmax, sv);
          }
      } else {
#pragma unroll
        for (int nf = 0; nf < 4; ++nf)
#pragma unroll
          for (int i = 0; i < 4; ++i) {
            float sv = sacc[nf][i] * scale;
            sacc[nf][i] = sv;
            pmax = fmaxf(pmax, sv);
          }
      }
      pmax = fmaxf(pmax, __shfl_xor(pmax, 16, 64));
      pmax = fmaxf(pmax, __shfl_xor(pmax, 32, 64));

      if (!__all(pmax <= mrow[s] + 8.0f)) {
        float mnew = fmaxf(mrow[s], pmax);
        float alpha = __expf(mrow[s] - mnew);
        mrow[s] = mnew;
        lsum[s] *= alpha;
#pragma unroll
        for (int i = 0; i < 4; ++i) {
          float al = __shfl(alpha, (lane & 48) | (lhi * 4 + i), 64);
#pragma unroll
          for (int df = 0; df < 8; ++df) acc[s][df][i] *= al;
        }
      }

      float rsum = 0.f;
      unsigned pk[4][2];
#pragma unroll
      for (int nf = 0; nf < 4; ++nf) {
        float p0 = __expf(sacc[nf][0] - mrow[s]);
        float p1 = __expf(sacc[nf][1] - mrow[s]);
        float p2 = __expf(sacc[nf][2] - mrow[s]);
        float p3 = __expf(sacc[nf][3] - mrow[s]);
        rsum += (p0 + p1) + (p2 + p3);
        pk[nf][0] = (unsigned)f2bf(p0) | ((unsigned)f2bf(p1) << 16);
        pk[nf][1] = (unsigned)f2bf(p2) | ((unsigned)f2bf(p3) << 16);
      }
      rsum += __shfl_xor(rsum, 16, 64);
      rsum += __shfl_xor(rsum, 32, 64);
      lsum[s] += rsum;

      s16x8 pa[2];
#pragma unroll
      for (int ph = 0; ph < 2; ++ph) {
        unsigned lo0 = __shfl((int)pk[2 * ph][0], sl0, 64);
        unsigned hi0 = __shfl((int)pk[2 * ph + 1][0], sl0, 64);
        unsigned lo1 = __shfl((int)pk[2 * ph][1], sl0, 64);
        unsigned hi1 = __shfl((int)pk[2 * ph + 1][1], sl0, 64);
        unsigned lo2 = __shfl((int)pk[2 * ph][0], sl1, 64);
        unsigned hi2 = __shfl((int)pk[2 * ph + 1][0], sl1, 64);
        unsigned lo3 = __shfl((int)pk[2 * ph][1], sl1, 64);
        unsigned hi3 = __shfl((int)pk[2 * ph + 1][1], sl1, 64);
        u32x4 w;
        w[0] = hisel ? hi0 : lo0;
        w[1] = hisel ? hi1 : lo1;
        w[2] = hisel ? hi2 : lo2;
        w[3] = hisel ? hi3 : lo3;
        pa[ph] = __builtin_bit_cast(s16x8, w);
      }

      __builtin_amdgcn_s_setprio(1);
#pragma unroll
      for (int ph = 0; ph < 2; ++ph) {
#pragma unroll
        for (int df = 0; df < 8; ++df) {
          s16x8 bb = *(const s16x8*)&Vts[VIDX(df * 16 + l15, ph * 32 + lhi * 8)];
          acc[s][df] = __builtin_amdgcn_mfma_f32_16x16x32_bf16(pa[ph], bb, acc[s][df], 0, 0, 0);
        }
      }
      __builtin_amdgcn_s_setprio(0);
    }
  }

#pragma unroll
  for (int s = 0; s < 2; ++s) {
    float rl = 1.0f / lsum[s];
#pragma unroll
    for (int i = 0; i < 4; ++i) {
      float rli = __shfl(rl, (lane & 48) | (lhi * 4 + i), 64);
      int m = b * S_LEN + qsub[s] * 128 + wave * 16 + lhi * 4 + i;
#pragma unroll
      for (int df = 0; df < 8; ++df) {
        int col = h * DHEAD + df * 16 + l15;
        ctx[(size_t)m * (NH_Q * DHEAD) + col] = f2bf(acc[s][df][i] * rli);
      }
    }
  }
}

extern "C" void kernel_launch(void* const* d_in, const int* in_sizes, int n_in,
                              void* d_out, int out_size, void* d_ws, size_t ws_size,
                              hipStream_t stream) {
  const float* x = (const float*)d_in[0];
  const int* positions = (const int*)d_in[1];
  const float* wq = (const float*)d_in[2];
  const float* wk = (const float*)d_in[3];
  const float* wv = (const float*)d_in[4];
  const float* wo = (const float*)d_in[5];
  float* out = (float*)d_out;

  char* ws = (char*)d_ws;
  const size_t MB1 = 1048576;
  const size_t SZ_X = 33554432;    // 2*2048*4096 bf16
  const size_t SZ_WQ = 33554432;   // 4096*4096 bf16
  const size_t SZ_WK = 8388608;    // 1024*4096 bf16
  const size_t NEED_FULL = MB1 + SZ_X + SZ_WQ + 2 * SZ_WK + SZ_WQ + 2 * SZ_WK;

  float* cos_t = (float*)ws;
  float* sin_t = (float*)(ws + MB1 / 2);

  rope_table_kernel<<<512, 256, 0, stream>>>(positions, cos_t, sin_t);

  if (ws_size >= NEED_FULL) {
    char* p = ws + MB1;
    u16* x_bf = (u16*)p;   p += SZ_X;       // later reused as ctx
    u16* w_bf = (u16*)p;   p += SZ_WQ;      // wq first, wo later
    u16* wkv_bf = (u16*)p; p += 2 * SZ_WK;  // wk | wv contiguous (2048 x 4096)
    u16* q_ws = (u16*)p;   p += SZ_WQ;
    u16* k_ws = (u16*)p;   p += SZ_WK;
    u16* v_ws = (u16*)p;   p += SZ_WK;      // V^T: [b][kvh][d][s]
    u16* ctx_ws = x_bf;

    cvt_kernel<<<2048, 256, 0, stream>>>(x, x_bf, 16777216 / 4);
    cvt_kernel<<<2048, 256, 0, stream>>>(wq, w_bf, 16777216 / 4);
    cvt_kernel<<<1024, 256, 0, stream>>>(wk, wkv_bf, 4194304 / 4);
    cvt_kernel<<<1024, 256, 0, stream>>>(wv, wkv_bf + 4194304, 4194304 / 4);

    gemm97_kernel<2><<<dim3(32, 32), 256, 0, stream>>>(
        x_bf, w_bf, q_ws, nullptr, 4096, 4096, 4096, cos_t, sin_t, NH_Q);
    cvt_kernel<<<2048, 256, 0, stream>>>(wo, w_bf, 16777216 / 4);  // w_bf now = wo_bf
    gemm97_kernel<3><<<dim3(16, 32), 256, 0, stream>>>(
        x_bf, wkv_bf, k_ws, v_ws, 4096, 2048, 4096, cos_t, sin_t, NKV_H);
    attn_kernel<<<dim3(8, 32, 2), 512, 0, stream>>>(q_ws, k_ws, v_ws, ctx_ws);
    gemm97_kernel<0><<<dim3(32, 32), 256, 0, stream>>>(
        ctx_ws, w_bf, out, nullptr, 4096, 4096, 4096, nullptr, nullptr, 0);
  } else {
    u16* q_ws = (u16*)(ws + MB1);
    u16* k_ws = (u16*)(ws + MB1 + SZ_WQ);
    u16* v_ws = (u16*)(ws + MB1 + SZ_WQ + SZ_WK);
    u16* ctx_ws = (u16*)(ws + MB1 + SZ_WQ + 2 * SZ_WK);

    gemm_kernel<2, false, false><<<dim3(32, 32), 256, 0, stream>>>(
        x, wq, q_ws, nullptr, 4096, 4096, 4096, cos_t, sin_t, NH_Q);
    gemm_kernel<2, false, false><<<dim3(8, 32), 256, 0, stream>>>(
        x, wk, k_ws, nullptr, 4096, 1024, 4096, cos_t, sin_t, NKV_H);
    gemm_kernel<4, false, false><<<dim3(8, 32), 256, 0, stream>>>(
        x, wv, v_ws, nullptr, 4096, 1024, 4096, nullptr, nullptr, NKV_H);
    attn_kernel<<<dim3(8, 32, 2), 512, 0, stream>>>(q_ws, k_ws, v_ws, ctx_ws);
    gemm_kernel<0, true, false><<<dim3(32, 32), 256, 0, stream>>>(
        ctx_ws, wo, out, nullptr, 4096, 4096, 4096, nullptr, nullptr, 0);
  }
}

// Round 6
// 608.724 us; speedup vs baseline: 1.2208x; 1.2208x over previous
//
#include <hip/hip_runtime.h>
#include <math.h>

typedef short s16x8 __attribute__((ext_vector_type(8)));
typedef float f32x4 __attribute__((ext_vector_type(4)));
typedef unsigned u32x4 __attribute__((ext_vector_type(4)));
typedef unsigned short u16;

#define S_LEN 2048
#define HID_DIM 4096
#define NH_Q 32
#define NKV_H 8
#define DHEAD 128

__device__ __forceinline__ u16 f2bf(float f) {
  unsigned u = __builtin_bit_cast(unsigned, f);
  u += 0x7fffu + ((u >> 16) & 1u);
  return (u16)(u >> 16);
}

// async global -> LDS, 16B per lane; lds base wave-uniform, lane*16 auto-offset
__device__ __forceinline__ void gload16(const u16* g, u16* l) {
  __builtin_amdgcn_global_load_lds(
      (const __attribute__((address_space(1))) void*)g,
      (__attribute__((address_space(3))) void*)l, 16, 0, 0);
}

// ---------------- f32 -> bf16 bulk convert ----------------
__global__ void cvt_kernel(const float* __restrict__ in, u16* __restrict__ out, int n4) {
  int stride = gridDim.x * blockDim.x;
  for (int i = blockIdx.x * blockDim.x + threadIdx.x; i < n4; i += stride) {
    float4 f = ((const float4*)in)[i];
    uint2 o;
    o.x = (unsigned)f2bf(f.x) | ((unsigned)f2bf(f.y) << 16);
    o.y = (unsigned)f2bf(f.z) | ((unsigned)f2bf(f.w) << 16);
    ((uint2*)out)[i] = o;
  }
}

// ---------------- RoPE tables: cos/sin [S][64] ----------------
__global__ void rope_table_kernel(const int* __restrict__ positions,
                                  float* __restrict__ cos_t, float* __restrict__ sin_t) {
  int idx = blockIdx.x * 256 + threadIdx.x;
  if (idx >= S_LEN * 64) return;
  int s = idx >> 6, j = idx & 63;
  float pos = (float)positions[s];
  float inv = expf(-(float)j * (9.210340371976184f / 64.0f));
  float ang = pos * inv;
  float sv, cv;
  sincosf(ang, &sv, &cv);
  cos_t[idx] = cv;
  sin_t[idx] = sv;
}

// ---------------- 256^2-tile 2-phase pipelined GEMM: C = A[M][K]*B[N][K]^T ----
// BK=32, 8 waves (2Mx4N), dbuf LDS 64KB, gload_lds staging (linear dest,
// inverse-swizzled source), T2 read-swizzle, raw barriers, vmcnt(0) only at
// K-tile boundary, T5 setprio around MFMA clusters.
// Wave (wr,wc): rows wr*128 + mf*16 (mf 0..7), cols wc*16 + nf*64 (nf 0..3)
// (64-separated col stripes keep RoPE pairs (j, j+64) in-wave).
// EPI: 0 = f32 row-major out; 5 = fused QKV epilogue (outp = q base;
//      k = q+16777216, v = k+4194304; Q/K RoPE'd [b][h][s][d], V^T [b][h][d][s])
template<int EPI>
__global__ __launch_bounds__(512) void gemm8p_kernel(
    const u16* __restrict__ A, const u16* __restrict__ B,
    void* __restrict__ outp, int M, int N, int K,
    const float* __restrict__ cos_t, const float* __restrict__ sin_t) {
  __shared__ u16 AsL[2][8192];  // [buf][half(2) x 128 rows x 32], 16KB each
  __shared__ u16 BsL[2][8192];
  const int t = threadIdx.x;
  const int wave = t >> 6, lane = t & 63;
  const int l15 = lane & 15, lhi = lane >> 4;
  const int wr = wave >> 2, wc = wave & 3;
  // bijective XCD swizzle (grids are multiples of 8)
  const int gx = gridDim.x;
  const int nwg = gx * gridDim.y;
  const int id = blockIdx.y * gx + blockIdx.x;
  const int swz = (id & 7) * (nwg >> 3) + (id >> 3);
  const int bm = (swz / gx) * 256, bn = (swz % gx) * 256;

  // staging constants: thread t covers (row = t>>2 in half, 16B slot = t&3 phys)
  // logical col = 8*((t&3) ^ ((t>>3)&3))  [inverse of read swizzle]
  const int srow = t >> 2;
  const int scol = 8 * ((t & 3) ^ ((t >> 3) & 3));
  const size_t ga0 = (size_t)(bm + srow) * K + scol;
  const size_t ga1 = (size_t)(bm + 128 + srow) * K + scol;
  const size_t gb0 = (size_t)(bn + srow) * K + scol;
  const size_t gb1 = (size_t)(bn + 128 + srow) * K + scol;
  const int ldst = wave * 512;  // + lane*8 elems implicit (lane*16B)

  // read-side swizzled fragment offsets (elems):
  // A frag mf: half wr, row rH = mf*16+l15, phys slot = lhi ^ ((l15>>1)&3)
  const int slotA = (lhi ^ ((l15 >> 1) & 3)) << 3;
  const int aidx = wr * 4096 + l15 * 32 + slotA;  // + mf*512
  int bidx[4];
#pragma unroll
  for (int nf = 0; nf < 4; ++nf)
    bidx[nf] = (nf >> 1) * 4096 + (wc * 16 + (nf & 1) * 64 + l15) * 32 + slotA;

  const f32x4 fz = {0.f, 0.f, 0.f, 0.f};
  f32x4 acc[8][4];
#pragma unroll
  for (int mf = 0; mf < 8; ++mf)
#pragma unroll
    for (int nf = 0; nf < 4; ++nf) acc[mf][nf] = fz;

  auto stage = [&](int tt) {
    const int b = tt & 1;
    const int kt = tt << 5;
    gload16(A + ga0 + kt, &AsL[b][ldst]);
    gload16(A + ga1 + kt, &AsL[b][4096 + ldst]);
    gload16(B + gb0 + kt, &BsL[b][ldst]);
    gload16(B + gb1 + kt, &BsL[b][4096 + ldst]);
  };

  const int nt = K >> 5;
  stage(0);
  asm volatile("s_waitcnt vmcnt(0)" ::: "memory");
  __builtin_amdgcn_s_barrier();

  for (int tt = 0; tt < nt; ++tt) {
    const u16* Ab = &AsL[tt & 1][0];
    const u16* Bb = &BsL[tt & 1][0];
    s16x8 af[4], bf[4];
    // ---- phase 1: reads + stage(t+1) | MFMA mf0-3 ----
#pragma unroll
    for (int mf = 0; mf < 4; ++mf) af[mf] = *(const s16x8*)&Ab[aidx + mf * 512];
#pragma unroll
    for (int nf = 0; nf < 4; ++nf) bf[nf] = *(const s16x8*)&Bb[bidx[nf]];
    if (tt + 1 < nt) stage(tt + 1);
    __builtin_amdgcn_s_barrier();
    __builtin_amdgcn_s_setprio(1);
#pragma unroll
    for (int mf = 0; mf < 4; ++mf)
#pragma unroll
      for (int nf = 0; nf < 4; ++nf)
        acc[mf][nf] = __builtin_amdgcn_mfma_f32_16x16x32_bf16(af[mf], bf[nf], acc[mf][nf], 0, 0, 0);
    __builtin_amdgcn_s_setprio(0);
    __builtin_amdgcn_s_barrier();
    // ---- phase 2: reads mf4-7 | MFMA mf4-7 | boundary vmcnt ----
#pragma unroll
    for (int mf = 0; mf < 4; ++mf) af[mf] = *(const s16x8*)&Ab[aidx + (mf + 4) * 512];
    __builtin_amdgcn_s_barrier();
    __builtin_amdgcn_s_setprio(1);
#pragma unroll
    for (int mf = 0; mf < 4; ++mf)
#pragma unroll
      for (int nf = 0; nf < 4; ++nf)
        acc[mf + 4][nf] =
            __builtin_amdgcn_mfma_f32_16x16x32_bf16(af[mf], bf[nf], acc[mf + 4][nf], 0, 0, 0);
    __builtin_amdgcn_s_setprio(0);
    asm volatile("s_waitcnt vmcnt(0)" ::: "memory");
    __builtin_amdgcn_s_barrier();
  }

  // ---- epilogue: row = bm + wr*128 + mf*16 + lhi*4 + i; col = bn + wc*16 + nf*64 + l15
  if (EPI == 0) {
    float* C = (float*)outp;
#pragma unroll
    for (int mf = 0; mf < 8; ++mf) {
      int rb = bm + wr * 128 + mf * 16 + lhi * 4;
#pragma unroll
      for (int nf = 0; nf < 4; ++nf) {
        int col = bn + wc * 16 + nf * 64 + l15;
#pragma unroll
        for (int i = 0; i < 4; ++i) C[(size_t)(rb + i) * N + col] = acc[mf][nf][i];
      }
    }
  } else {  // EPI == 5: fused QKV
    u16* qp = (u16*)outp;
    u16* kp = qp + 16777216;  // 2*32*2048*128
    u16* vp = kp + 4194304;   // 2*8*2048*128
    if (bn < 4096 || (bn >= 4096 && bn < 5120)) {
      const bool isQ = bn < 4096;
      u16* O = isQ ? qp : kp;
      const int hb = isQ ? (bn >> 7) : ((bn - 4096) >> 7);
      const int Hh = isQ ? NH_Q : NKV_H;
      const int j = wc * 16 + l15;  // 0..63
#pragma unroll
      for (int mf = 0; mf < 8; ++mf) {
        int rb = bm + wr * 128 + mf * 16 + lhi * 4;
#pragma unroll
        for (int p = 0; p < 2; ++p) {
          int head = hb + p;
#pragma unroll
          for (int i = 0; i < 4; ++i) {
            int m = rb + i;
            int b = m >> 11, srw = m & 2047;
            float c = cos_t[srw * 64 + j];
            float s = sin_t[srw * 64 + j];
            float x0 = acc[mf][2 * p][i];
            float x1 = acc[mf][2 * p + 1][i];
            size_t base = ((size_t)(b * Hh + head) * S_LEN + srw) * DHEAD;
            O[base + j] = f2bf(x0 * c - x1 * s);
            O[base + j + 64] = f2bf(x0 * s + x1 * c);
          }
        }
      }
    } else {  // V transposed [b][h][d][s]
#pragma unroll
      for (int mf = 0; mf < 8; ++mf) {
        int rb = bm + wr * 128 + mf * 16 + lhi * 4;
#pragma unroll
        for (int nf = 0; nf < 4; ++nf) {
          int colrel = bn - 5120 + wc * 16 + nf * 64 + l15;
          int head = colrel >> 7, d = colrel & 127;
#pragma unroll
          for (int i = 0; i < 4; ++i) {
            int m = rb + i;
            int b = m >> 11, srw = m & 2047;
            vp[((size_t)(b * NKV_H + head) * DHEAD + d) * S_LEN + srw] = f2bf(acc[mf][nf][i]);
          }
        }
      }
    }
  }
}

// ---------------- reg-staged GEMM (fallback path only) ----------------
template<int EPI, bool ABF16, bool BBF16>
__global__ __launch_bounds__(256) void gemm_kernel(
    const void* __restrict__ Aptr, const void* __restrict__ Bptr,
    void* __restrict__ outp, void* __restrict__ outp2, int M, int N, int K,
    const float* __restrict__ cos_t, const float* __restrict__ sin_t, int Hh) {
  __shared__ u16 As[128][72];
  __shared__ u16 Bs[128][72];
  const int t = threadIdx.x;
  const int wave = t >> 6, lane = t & 63;
  const int l15 = lane & 15, lhi = lane >> 4;
  const int gx = gridDim.x;
  const int nwg = gx * gridDim.y;
  const int id = blockIdx.y * gx + blockIdx.x;
  const int swz = (id & 7) * (nwg >> 3) + (id >> 3);
  const int bm = (swz / gx) * 128, bn = (swz % gx) * 128;

  const f32x4 fz = {0.f, 0.f, 0.f, 0.f};
  f32x4 acc[2][8];
#pragma unroll
  for (int a0 = 0; a0 < 2; ++a0)
#pragma unroll
    for (int b0 = 0; b0 < 8; ++b0) acc[a0][b0] = fz;

  for (int kt = 0; kt < K; kt += 64) {
    __syncthreads();
    if (ABF16) {
      const u16* A = (const u16*)Aptr;
#pragma unroll
      for (int p = 0; p < 4; ++p) {
        int row = p * 32 + (t >> 3), kc = (t & 7) * 8;
        *(s16x8*)&As[row][kc] = *(const s16x8*)(A + (size_t)(bm + row) * K + kt + kc);
      }
    } else {
      const float* A = (const float*)Aptr;
#pragma unroll
      for (int p = 0; p < 8; ++p) {
        int row = p * 16 + (t >> 4), kc = (t & 15) * 4;
        float4 f = *(const float4*)(A + (size_t)(bm + row) * K + kt + kc);
        unsigned* dst = (unsigned*)&As[row][kc];
        dst[0] = (unsigned)f2bf(f.x) | ((unsigned)f2bf(f.y) << 16);
        dst[1] = (unsigned)f2bf(f.z) | ((unsigned)f2bf(f.w) << 16);
      }
    }
    if (BBF16) {
      const u16* Bw = (const u16*)Bptr;
#pragma unroll
      for (int p = 0; p < 4; ++p) {
        int row = p * 32 + (t >> 3), kc = (t & 7) * 8;
        *(s16x8*)&Bs[row][kc] = *(const s16x8*)(Bw + (size_t)(bn + row) * K + kt + kc);
      }
    } else {
      const float* Bw = (const float*)Bptr;
#pragma unroll
      for (int p = 0; p < 8; ++p) {
        int row = p * 16 + (t >> 4), kc = (t & 15) * 4;
        float4 f = *(const float4*)(Bw + (size_t)(bn + row) * K + kt + kc);
        unsigned* dst = (unsigned*)&Bs[row][kc];
        dst[0] = (unsigned)f2bf(f.x) | ((unsigned)f2bf(f.y) << 16);
        dst[1] = (unsigned)f2bf(f.z) | ((unsigned)f2bf(f.w) << 16);
      }
    }
    __syncthreads();
#pragma unroll
    for (int ks = 0; ks < 2; ++ks) {
      s16x8 bfr[8];
#pragma unroll
      for (int nf = 0; nf < 8; ++nf)
        bfr[nf] = *(const s16x8*)&Bs[nf * 16 + l15][ks * 32 + lhi * 8];
#pragma unroll
      for (int mf = 0; mf < 2; ++mf) {
        s16x8 a = *(const s16x8*)&As[wave * 32 + mf * 16 + l15][ks * 32 + lhi * 8];
#pragma unroll
        for (int nf = 0; nf < 8; ++nf)
          acc[mf][nf] = __builtin_amdgcn_mfma_f32_16x16x32_bf16(a, bfr[nf], acc[mf][nf], 0, 0, 0);
      }
    }
  }

  if (EPI == 0) {
    float* C = (float*)outp;
#pragma unroll
    for (int mf = 0; mf < 2; ++mf)
#pragma unroll
      for (int nf = 0; nf < 8; ++nf) {
        int col = bn + nf * 16 + l15;
        int rb = bm + wave * 32 + mf * 16 + lhi * 4;
#pragma unroll
        for (int i = 0; i < 4; ++i) C[(size_t)(rb + i) * N + col] = acc[mf][nf][i];
      }
  } else if (EPI == 2) {
    u16* O = (u16*)outp;
    int h = bn >> 7;
#pragma unroll
    for (int mf = 0; mf < 2; ++mf)
#pragma unroll
      for (int nf = 0; nf < 4; ++nf) {
        int j = nf * 16 + l15;
        int rb = bm + wave * 32 + mf * 16 + lhi * 4;
#pragma unroll
        for (int i = 0; i < 4; ++i) {
          int m = rb + i;
          int b = m >> 11, srow = m & 2047;
          float c = cos_t[srow * 64 + j];
          float s = sin_t[srow * 64 + j];
          float x0 = acc[mf][nf][i];
          float x1 = acc[mf][nf + 4][i];
          size_t base = ((size_t)(b * Hh + h) * S_LEN + srow) * DHEAD;
          O[base + j] = f2bf(x0 * c - x1 * s);
          O[base + j + 64] = f2bf(x0 * s + x1 * c);
        }
      }
  } else {  // EPI == 4: bf16 transposed [b][h][d][s]
    u16* O = (u16*)outp;
#pragma unroll
    for (int mf = 0; mf < 2; ++mf)
#pragma unroll
      for (int nf = 0; nf < 8; ++nf) {
        int col = bn + nf * 16 + l15;
        int h = col >> 7, d = col & 127;
        int rb = bm + wave * 32 + mf * 16 + lhi * 4;
#pragma unroll
        for (int i = 0; i < 4; ++i) {
          int m = rb + i;
          int b = m >> 11, srow = m & 2047;
          O[((size_t)(b * Hh + h) * DHEAD + d) * S_LEN + srow] = f2bf(acc[mf][nf][i]);
        }
      }
  }
}

// ---------------- Flash attention (causal, GQA) ----------------
#define KIDX(r, c) (((r) * 128 + (c)) ^ (((r) & 7) << 3))
#define VIDX(d, kv) (((d) * 64 + (kv)) ^ (((d) & 7) << 3))
__global__ __launch_bounds__(512) void attn_kernel(
    const u16* __restrict__ q, const u16* __restrict__ k, const u16* __restrict__ vt,
    u16* __restrict__ ctx) {
  __shared__ u16 Ks[64 * 128];
  __shared__ u16 Vts[128 * 64];

  const int t = threadIdx.x;
  const int wave = t >> 6, lane = t & 63;
  const int l15 = lane & 15, lhi = lane >> 4;
  const int pi = blockIdx.x, h = blockIdx.y, b = blockIdx.z;
  const int kvh = h >> 2;
  const int qsub[2] = {pi, 15 - pi};
  const int ntiles = 32 - 2 * pi;

  const u16* qb = q + ((size_t)(b * NH_Q + h)) * S_LEN * DHEAD;
  const u16* kb = k + ((size_t)(b * NKV_H + kvh)) * S_LEN * DHEAD;
  const u16* vtb = vt + ((size_t)(b * NKV_H + kvh)) * DHEAD * S_LEN;

  s16x8 qf[2][4];
#pragma unroll
  for (int s = 0; s < 2; ++s)
#pragma unroll
    for (int ks = 0; ks < 4; ++ks)
      qf[s][ks] = *(const s16x8*)(qb + (size_t)(qsub[s] * 128 + wave * 16 + l15) * DHEAD +
                                  ks * 32 + lhi * 8);

  const f32x4 fz = {0.f, 0.f, 0.f, 0.f};
  f32x4 acc[2][8];
#pragma unroll
  for (int s = 0; s < 2; ++s)
#pragma unroll
    for (int i = 0; i < 8; ++i) acc[s][i] = fz;
  float mrow[2] = {-INFINITY, -INFINITY};
  float lsum[2] = {0.f, 0.f};

  const float scale = 0.08838834764831845f;

  const int sl0 = l15 | (((2 * lhi) & 3) << 4);
  const int sl1 = sl0 | 16;
  const bool hisel = (lhi & 2) != 0;

  const int krow = t >> 3, kd0 = (t & 7) * 16;
  const int vrow = t >> 2, vk0 = (t & 3) * 16;
  s16x8 kr0, kr1, vr0, vr1;
  {
    const u16* p = kb + (size_t)krow * DHEAD + kd0;
    kr0 = *(const s16x8*)p;
    kr1 = *(const s16x8*)(p + 8);
    const u16* pv = vtb + (size_t)vrow * S_LEN + vk0;
    vr0 = *(const s16x8*)pv;
    vr1 = *(const s16x8*)(pv + 8);
  }

  for (int tt = 0; tt < ntiles; ++tt) {
    __syncthreads();
    *(s16x8*)&Ks[KIDX(krow, kd0)] = kr0;
    *(s16x8*)&Ks[KIDX(krow, kd0 + 8)] = kr1;
    *(s16x8*)&Vts[VIDX(vrow, vk0)] = vr0;
    *(s16x8*)&Vts[VIDX(vrow, vk0 + 8)] = vr1;
    __syncthreads();
    if (tt + 1 < ntiles) {
      const u16* p = kb + (size_t)((tt + 1) * 64 + krow) * DHEAD + kd0;
      kr0 = *(const s16x8*)p;
      kr1 = *(const s16x8*)(p + 8);
      const u16* pv = vtb + (size_t)vrow * S_LEN + (tt + 1) * 64 + vk0;
      vr0 = *(const s16x8*)pv;
      vr1 = *(const s16x8*)(pv + 8);
    }

    const int kc_base = tt * 64;
#pragma unroll
    for (int s = 0; s < 2; ++s) {
      const int wmin = qsub[s] * 128 + wave * 16;
      if (kc_base > wmin + 15) continue;
      f32x4 sacc[4];
#pragma unroll
      for (int i = 0; i < 4; ++i) sacc[i] = fz;
      __builtin_amdgcn_s_setprio(1);
#pragma unroll
      for (int ks = 0; ks < 4; ++ks) {
#pragma unroll
        for (int nf = 0; nf < 4; ++nf) {
          s16x8 kf = *(const s16x8*)&Ks[KIDX(nf * 16 + l15, ks * 32 + lhi * 8)];
          sacc[nf] = __builtin_amdgcn_mfma_f32_16x16x32_bf16(kf, qf[s][ks], sacc[nf], 0, 0, 0);
        }
      }
      __builtin_amdgcn_s_setprio(0);

      const int qg = wmin + l15;
      float pmax = -INFINITY;
      if (kc_base + 63 > wmin) {
#pragma unroll
        for (int nf = 0; nf < 4; ++nf)
#pragma unroll
          for (int i = 0; i < 4; ++i) {
            int kv = kc_base + nf * 16 + lhi * 4 + i;
            float sv = sacc[nf][i] * scale;
            sv = (kv <= qg) ? sv : -INFINITY;
            sacc[nf][i] = sv;
            pmax = fmaxf(pmax, sv);
          }
      } else {
#pragma unroll
        for (int nf = 0; nf < 4; ++nf)
#pragma unroll
          for (int i = 0; i < 4; ++i) {
            float sv = sacc[nf][i] * scale;
            sacc[nf][i] = sv;
            pmax = fmaxf(pmax, sv);
          }
      }
      pmax = fmaxf(pmax, __shfl_xor(pmax, 16, 64));
      pmax = fmaxf(pmax, __shfl_xor(pmax, 32, 64));

      if (!__all(pmax <= mrow[s] + 8.0f)) {
        float mnew = fmaxf(mrow[s], pmax);
        float alpha = __expf(mrow[s] - mnew);
        mrow[s] = mnew;
        lsum[s] *= alpha;
#pragma unroll
        for (int i = 0; i < 4; ++i) {
          float al = __shfl(alpha, (lane & 48) | (lhi * 4 + i), 64);
#pragma unroll
          for (int df = 0; df < 8; ++df) acc[s][df][i] *= al;
        }
      }

      float rsum = 0.f;
      unsigned pk[4][2];
#pragma unroll
      for (int nf = 0; nf < 4; ++nf) {
        float p0 = __expf(sacc[nf][0] - mrow[s]);
        float p1 = __expf(sacc[nf][1] - mrow[s]);
        float p2 = __expf(sacc[nf][2] - mrow[s]);
        float p3 = __expf(sacc[nf][3] - mrow[s]);
        rsum += (p0 + p1) + (p2 + p3);
        pk[nf][0] = (unsigned)f2bf(p0) | ((unsigned)f2bf(p1) << 16);
        pk[nf][1] = (unsigned)f2bf(p2) | ((unsigned)f2bf(p3) << 16);
      }
      rsum += __shfl_xor(rsum, 16, 64);
      rsum += __shfl_xor(rsum, 32, 64);
      lsum[s] += rsum;

      s16x8 pa[2];
#pragma unroll
      for (int ph = 0; ph < 2; ++ph) {
        unsigned lo0 = __shfl((int)pk[2 * ph][0], sl0, 64);
        unsigned hi0 = __shfl((int)pk[2 * ph + 1][0], sl0, 64);
        unsigned lo1 = __shfl((int)pk[2 * ph][1], sl0, 64);
        unsigned hi1 = __shfl((int)pk[2 * ph + 1][1], sl0, 64);
        unsigned lo2 = __shfl((int)pk[2 * ph][0], sl1, 64);
        unsigned hi2 = __shfl((int)pk[2 * ph + 1][0], sl1, 64);
        unsigned lo3 = __shfl((int)pk[2 * ph][1], sl1, 64);
        unsigned hi3 = __shfl((int)pk[2 * ph + 1][1], sl1, 64);
        u32x4 w;
        w[0] = hisel ? hi0 : lo0;
        w[1] = hisel ? hi1 : lo1;
        w[2] = hisel ? hi2 : lo2;
        w[3] = hisel ? hi3 : lo3;
        pa[ph] = __builtin_bit_cast(s16x8, w);
      }

      __builtin_amdgcn_s_setprio(1);
#pragma unroll
      for (int ph = 0; ph < 2; ++ph) {
#pragma unroll
        for (int df = 0; df < 8; ++df) {
          s16x8 bb = *(const s16x8*)&Vts[VIDX(df * 16 + l15, ph * 32 + lhi * 8)];
          acc[s][df] = __builtin_amdgcn_mfma_f32_16x16x32_bf16(pa[ph], bb, acc[s][df], 0, 0, 0);
        }
      }
      __builtin_amdgcn_s_setprio(0);
    }
  }

#pragma unroll
  for (int s = 0; s < 2; ++s) {
    float rl = 1.0f / lsum[s];
#pragma unroll
    for (int i = 0; i < 4; ++i) {
      float rli = __shfl(rl, (lane & 48) | (lhi * 4 + i), 64);
      int m = b * S_LEN + qsub[s] * 128 + wave * 16 + lhi * 4 + i;
#pragma unroll
      for (int df = 0; df < 8; ++df) {
        int col = h * DHEAD + df * 16 + l15;
        ctx[(size_t)m * (NH_Q * DHEAD) + col] = f2bf(acc[s][df][i] * rli);
      }
    }
  }
}

extern "C" void kernel_launch(void* const* d_in, const int* in_sizes, int n_in,
                              void* d_out, int out_size, void* d_ws, size_t ws_size,
                              hipStream_t stream) {
  const float* x = (const float*)d_in[0];
  const int* positions = (const int*)d_in[1];
  const float* wq = (const float*)d_in[2];
  const float* wk = (const float*)d_in[3];
  const float* wv = (const float*)d_in[4];
  const float* wo = (const float*)d_in[5];
  float* out = (float*)d_out;

  char* ws = (char*)d_ws;
  const size_t MB1 = 1048576;
  const size_t SZ_X = 33554432;     // 2*2048*4096 bf16
  const size_t SZ_WQKV = 50331648;  // 6144*4096 bf16
  const size_t SZ_Q = 33554432;     // q bf16
  const size_t SZ_WK = 8388608;     // k or v bf16
  const size_t NEED_FULL = MB1 + SZ_X + SZ_WQKV + SZ_Q + 2 * SZ_WK;  // 129 MB

  float* cos_t = (float*)ws;
  float* sin_t = (float*)(ws + MB1 / 2);

  rope_table_kernel<<<512, 256, 0, stream>>>(positions, cos_t, sin_t);

  if (ws_size >= NEED_FULL) {
    char* p = ws + MB1;
    u16* x_bf = (u16*)p;    p += SZ_X;     // later reused as ctx
    u16* wqkv_bf = (u16*)p; p += SZ_WQKV;  // wq|wk|wv stacked; wo after QKV gemm
    u16* q_ws = (u16*)p;    p += SZ_Q;     // q | k | v contiguous
    u16* k_ws = (u16*)p;    p += SZ_WK;
    u16* v_ws = (u16*)p;    p += SZ_WK;
    u16* ctx_ws = x_bf;

    cvt_kernel<<<2048, 256, 0, stream>>>(x, x_bf, 4194304);
    cvt_kernel<<<2048, 256, 0, stream>>>(wq, wqkv_bf, 4194304);
    cvt_kernel<<<1024, 256, 0, stream>>>(wk, wqkv_bf + 16777216, 1048576);
    cvt_kernel<<<1024, 256, 0, stream>>>(wv, wqkv_bf + 20971520, 1048576);

    // fused QKV: N = 6144 (cols 0-4095 Q, 4096-5119 K, 5120-6143 V)
    gemm8p_kernel<5><<<dim3(24, 16), 512, 0, stream>>>(
        x_bf, wqkv_bf, q_ws, 4096, 6144, 4096, cos_t, sin_t);
    cvt_kernel<<<2048, 256, 0, stream>>>(wo, wqkv_bf, 4194304);  // wqkv_bf now = wo_bf
    attn_kernel<<<dim3(8, 32, 2), 512, 0, stream>>>(q_ws, k_ws, v_ws, ctx_ws);
    gemm8p_kernel<0><<<dim3(16, 16), 512, 0, stream>>>(
        ctx_ws, wqkv_bf, out, 4096, 4096, 4096, nullptr, nullptr);
  } else {
    u16* q_ws = (u16*)(ws + MB1);
    u16* k_ws = (u16*)(ws + MB1 + SZ_Q);
    u16* v_ws = (u16*)(ws + MB1 + SZ_Q + SZ_WK);
    u16* ctx_ws = (u16*)(ws + MB1 + SZ_Q + 2 * SZ_WK);

    gemm_kernel<2, false, false><<<dim3(32, 32), 256, 0, stream>>>(
        x, wq, q_ws, nullptr, 4096, 4096, 4096, cos_t, sin_t, NH_Q);
    gemm_kernel<2, false, false><<<dim3(8, 32), 256, 0, stream>>>(
        x, wk, k_ws, nullptr, 4096, 1024, 4096, cos_t, sin_t, NKV_H);
    gemm_kernel<4, false, false><<<dim3(8, 32), 256, 0, stream>>>(
        x, wv, v_ws, nullptr, 4096, 1024, 4096, nullptr, nullptr, NKV_H);
    attn_kernel<<<dim3(8, 32, 2), 512, 0, stream>>>(q_ws, k_ws, v_ws, ctx_ws);
    gemm_kernel<0, true, false><<<dim3(32, 32), 256, 0, stream>>>(
        ctx_ws, wo, out, nullptr, 4096, 4096, 4096, nullptr, nullptr, 0);
  }
}